// Round 7
// baseline (356.814 us; speedup 1.0000x reference)
//
#include <hip/hip_runtime.h>

#define EDGES   800000
#define IN_F    64
#define HID     128
#define TPB     1024                // 16 waves per WG
#define EPW     16                  // edges per wave = one 16-col MFMA tile
#define EPB     256                 // edges per WG (16 waves * 16)
#define NBLK    (EDGES / EPB)       // 3125 edge blocks
#define GRID    256                 // persistent: 1 WG/CU, 4 waves/SIMD

// LDS: [w1 16K | w2 32K | w3 32K | b1 | b2 | b3 | w4 | H: 16 waves x 4K]
// f16 weights XOR-swizzled by row; H = per-wave activation staging, XOR-swizzled.
#define W1_OFF  0
#define W2_OFF  16384
#define W3_OFF  49152
#define B1_OFF  81920
#define B2_OFF  82432
#define B3_OFF  82944
#define W4_OFF  83456
#define H_OFF   83968
#define LDSB    (H_OFF + 16 * 4096) // 149504 <= 160 KiB

typedef _Float16 half8  __attribute__((ext_vector_type(8)));
typedef __fp16   fp16x2 __attribute__((ext_vector_type(2)));
typedef float    f32x4  __attribute__((ext_vector_type(4)));
typedef unsigned u32;
typedef u32      u32x2  __attribute__((ext_vector_type(2)));

__device__ __forceinline__ float fast_tanh(float x) {
    // tanh(x) = 1 - 2/(e^{2x}+1); preacts bounded, no overflow.
    float e = __builtin_amdgcn_exp2f(2.8853900817779268f * x);
    return 1.0f - 2.0f * __builtin_amdgcn_rcpf(e + 1.0f);
}
__device__ __forceinline__ float fast_sigmoid(float x) {
    return __builtin_amdgcn_rcpf(1.0f + __builtin_amdgcn_exp2f(-1.4426950408889634f * x));
}
__device__ __forceinline__ u32 pk2(float a, float b) {
    fp16x2 p = __builtin_amdgcn_cvt_pkrtz(a, b);
    return __builtin_bit_cast(u32, p);
}
__device__ __forceinline__ half8 cvt8(float4 a, float4 b) {
    half8 h;
    h[0]=(_Float16)a.x; h[1]=(_Float16)a.y; h[2]=(_Float16)a.z; h[3]=(_Float16)a.w;
    h[4]=(_Float16)b.x; h[5]=(_Float16)b.y; h[6]=(_Float16)b.z; h[7]=(_Float16)b.w;
    return h;
}
__device__ __forceinline__ f32x4 mfma16(half8 a, half8 b, f32x4 c) {
    return __builtin_amdgcn_mfma_f32_16x16x32_f16(a, b, c, 0, 0, 0);
}

// 16x16x32 layouts (family-verified; direct analog of the 32x32x16 we verified
// in rounds 1-6):
//   A (weights): lane l holds W[row = 16it + (l&15)][k = (l>>4)*8 + j]
//   B (acts):    lane l holds Act[k = (l>>4)*8 + j][edge = l&15]
//   D:           lane l reg r holds O[h' = 16it + 4*(l>>4) + r][edge = l&15]
// -> per lane 4 consecutive h' at fixed edge: one packed ds_write_b64 to H,
//    and the next layer's B-frag is a natural b128 read of H[edge].
//
// Occupancy design (round-6 post-mortem): 140us at VALUBusy 51% was
// latency-bound at 2 waves/SIMD. 16x16 tile halves per-wave H (4KB) so a
// 16-wave WG fits the same 149504B LDS -> 4 waves/SIMD. launch_bounds(1024)
// alone forces VGPR<=128 (16-wave WG must co-reside) without the 64-cap trap.
__global__ __launch_bounds__(TPB)
void gnn_mlp(const float* __restrict__ ea,
             const float* __restrict__ W1, const float* __restrict__ b1,
             const float* __restrict__ W2, const float* __restrict__ b2,
             const float* __restrict__ W3, const float* __restrict__ b3,
             const float* __restrict__ W4, const float* __restrict__ b4,
             float* __restrict__ out) {
    __shared__ __align__(16) char LW[LDSB];

    const int tid  = threadIdx.x;
    const int lane = tid & 63;
    const int wv   = tid >> 6;          // wave 0..15
    const int col  = lane & 15;         // edge column of the 16x16 tile
    const int q    = lane >> 4;         // k-quarter selector 0..3

    // ---- stage weights: f32 -> f16, XOR-swizzled by row, once per WG ----
    // swizzle: phys = off ^ ((row&7)<<4) for 128B rows (w1)
    //          phys = off ^ ((row&15)<<4) for 256B rows (w2/w3)
    #pragma unroll
    for (int i = 0; i < 5; ++i) {
        const int g   = i * TPB + tid;  // 16B granule id, 5120 total
        const int off = g << 4;
        const float* src; int phys;
        if (i == 0) {                   // w1: granules 0..1023
            int row = off >> 7;
            phys = W1_OFF + (off ^ ((row & 7) << 4));
            src  = W1 + (off >> 1);
        } else if (i <= 2) {            // w2: granules 1024..3071
            int rel = off - W2_OFF, row = rel >> 8;
            phys = W2_OFF + (rel ^ ((row & 15) << 4));
            src  = W2 + (rel >> 1);
        } else {                        // w3: granules 3072..5119
            int rel = off - W3_OFF, row = rel >> 8;
            phys = W3_OFF + (rel ^ ((row & 15) << 4));
            src  = W3 + (rel >> 1);
        }
        float4 a = *(const float4*)(src);
        float4 b = *(const float4*)(src + 4);
        *(half8*)(LW + phys) = cvt8(a, b);
    }
    // ---- stage biases + W4 (f32) ----
    if (tid < 128)      *(float*)(LW + B1_OFF + tid * 4)         = b1[tid];
    else if (tid < 256) *(float*)(LW + B2_OFF + (tid - 128) * 4) = b2[tid - 128];
    else if (tid < 384) *(float*)(LW + B3_OFF + (tid - 256) * 4) = b3[tid - 256];
    else if (tid < 512) *(float*)(LW + W4_OFF + (tid - 384) * 4) = W4[tid - 384];
    __syncthreads();   // only barrier in the kernel

    const int q16  = q << 4;
    const int q8   = q << 3;
    const u32 hsw  = (u32)((col & 7) << 4);   // H swizzle AND w1 swizzle (row&7 = col&7)
    const u32 wsw2 = (u32)(col << 4);         // w2/w3 swizzle (row&15 = col)
    // per-lane swizzled in-row read offsets (k-step s, quarter q)
    const int oh0 = (0*64 + q16) ^ (int)hsw,  oh1 = (1*64 + q16) ^ (int)hsw,
              oh2 = (2*64 + q16) ^ (int)hsw,  oh3 = (3*64 + q16) ^ (int)hsw;
    const int ow0 = (0*64 + q16) ^ (int)wsw2, ow1 = (1*64 + q16) ^ (int)wsw2,
              ow2 = (2*64 + q16) ^ (int)wsw2, ow3 = (3*64 + q16) ^ (int)wsw2;

    const char* LW1 = LW + W1_OFF;
    const char* LW2 = LW + W2_OFF;
    const char* LW3 = LW + W3_OFF;
    const char* LB1 = LW + B1_OFF + q16;
    const char* LB2 = LW + B2_OFF + q16;
    const char* LB3 = LW + B3_OFF + q16;
    const char* LV4 = LW + W4_OFF + q16;
    char*       HB  = LW + H_OFF + wv * 4096 + col * 256;   // wave-private rows
    const float bb  = b4[0];

    // H store: D regs r=0..3 are h' = 16it+4q+r -> byte off = 32it+8q, b64,
    // phys = byte ^ hsw (pure per-byte XOR, identical on read side).
#define STORE_T(IT, A) *(u32x2*)(HB + ((32*(IT) + q8) ^ (int)hsw)) = \
    (u32x2){ pk2(fast_tanh((A)[0]), fast_tanh((A)[1])), \
             pk2(fast_tanh((A)[2]), fast_tanh((A)[3])) }

#define BIAS4(P, IT) ({ float4 bv_ = *(const float4*)((P) + (IT)*64); \
    (f32x4){bv_.x, bv_.y, bv_.z, bv_.w}; })

    // ---- half-depth prefetch: next block's k in [0,32) (8 regs) ----
    {
        const float* ep = ea + ((long)blockIdx.x * EPB + wv * EPW + col) * IN_F + q * 8;
        float4 s0 = *(const float4*)(ep);
        float4 s1 = *(const float4*)(ep + 4);

        for (int blk = blockIdx.x; blk < NBLK; blk += GRID) {
            const long ebase = (long)blk * EPB + wv * EPW;
            const float* ec = ea + (ebase + col) * IN_F + q * 8;

            float4 c0 = *(const float4*)(ec + 32);   // current k in [32,64)
            float4 c1 = *(const float4*)(ec + 36);

            half8 f1_0 = cvt8(s0, s1);
            if (blk + GRID < NBLK) {                 // issue next block's first half
                const float* en = ea + ((long)(blk + GRID) * EPB + wv * EPW + col) * IN_F + q * 8;
                s0 = *(const float4*)(en);
                s1 = *(const float4*)(en + 4);
            }
            half8 f1_1 = cvt8(c0, c1);

            // ---- layer 1: 64 -> 128 (8 tiles x 2 k-steps), results to H ----
#define L1T(IT) { f32x4 a = BIAS4(LB1, IT); \
            const char* wr = LW1 + (16*(IT) + col) * 128; \
            a = mfma16(*(const half8*)(wr + oh0), f1_0, a); \
            a = mfma16(*(const half8*)(wr + oh1), f1_1, a); \
            STORE_T(IT, a); }
            L1T(0); L1T(1); L1T(2); L1T(3); L1T(4); L1T(5); L1T(6); L1T(7);
#undef L1T

            // ---- layer 2: 128 -> 128 (8 tiles x 4 k-steps) ----
            {
                half8 g0 = *(const half8*)(HB + oh0), g1 = *(const half8*)(HB + oh1),
                      g2 = *(const half8*)(HB + oh2), g3 = *(const half8*)(HB + oh3);
#define L2T(IT) { f32x4 a = BIAS4(LB2, IT); \
                const char* wr = LW2 + (16*(IT) + col) * 256; \
                a = mfma16(*(const half8*)(wr + ow0), g0, a); \
                a = mfma16(*(const half8*)(wr + ow1), g1, a); \
                a = mfma16(*(const half8*)(wr + ow2), g2, a); \
                a = mfma16(*(const half8*)(wr + ow3), g3, a); \
                STORE_T(IT, a); }
                L2T(0); L2T(1); L2T(2); L2T(3); L2T(4); L2T(5); L2T(6); L2T(7);
#undef L2T
            }

            // ---- layer 3 + fused layer-4 dot (no H write) ----
            float p = 0.0f;
            {
                half8 g0 = *(const half8*)(HB + oh0), g1 = *(const half8*)(HB + oh1),
                      g2 = *(const half8*)(HB + oh2), g3 = *(const half8*)(HB + oh3);
#define L3T(IT) { f32x4 a = BIAS4(LB3, IT); \
                const char* wr = LW3 + (16*(IT) + col) * 256; \
                a = mfma16(*(const half8*)(wr + ow0), g0, a); \
                a = mfma16(*(const half8*)(wr + ow1), g1, a); \
                a = mfma16(*(const half8*)(wr + ow2), g2, a); \
                a = mfma16(*(const half8*)(wr + ow3), g3, a); \
                float4 w4v = *(const float4*)(LV4 + (IT)*64); \
                p += fast_tanh(a[0])*w4v.x + fast_tanh(a[1])*w4v.y \
                   + fast_tanh(a[2])*w4v.z + fast_tanh(a[3])*w4v.w; }
                L3T(0); L3T(1); L3T(2); L3T(3); L3T(4); L3T(5); L3T(6); L3T(7);
#undef L3T
            }

            // sum over hidden: partials live in the 4 lanes sharing col (q=0..3)
            p += __shfl_xor(p, 16, 64);
            p += __shfl_xor(p, 32, 64);
            if (lane < 16) out[ebase + col] = fast_sigmoid(p + bb);
        }
    }
}

extern "C" void kernel_launch(void* const* d_in, const int* in_sizes, int n_in,
                              void* d_out, int out_size, void* d_ws, size_t ws_size,
                              hipStream_t stream) {
    // setup_inputs order: x, edge_index, edge_attr, W1,b1, W2,b2, W3,b3, W4,b4
    const float* ea = (const float*)d_in[2];
    const float* W1 = (const float*)d_in[3];
    const float* b1 = (const float*)d_in[4];
    const float* W2 = (const float*)d_in[5];
    const float* b2 = (const float*)d_in[6];
    const float* W3 = (const float*)d_in[7];
    const float* b3 = (const float*)d_in[8];
    const float* W4 = (const float*)d_in[9];
    const float* b4 = (const float*)d_in[10];
    float* out = (float*)d_out;

    hipLaunchKernelGGL(gnn_mlp, dim3(GRID), dim3(TPB), 0, stream,
                       ea, W1, b1, W2, b2, W3, b3, W4, b4, out);
}